// Round 5
// baseline (277.393 us; speedup 1.0000x reference)
//
#include <hip/hip_runtime.h>
#include <math.h>

#define HH 96
#define WW 96
#define CC 64
#define NH 4
#define HD 16
#define KS 13
#define NTOK (HH*WW)

// ---------------- LayerNorm (LN1): one wave per token ----------------
__global__ __launch_bounds__(256) void ln_kernel(const float* __restrict__ x,
                                                 const float* __restrict__ g,
                                                 const float* __restrict__ b,
                                                 float* __restrict__ out) {
    int wave = threadIdx.x >> 6;
    int lane = threadIdx.x & 63;
    int token = blockIdx.x * 4 + wave;
    float v = x[token * CC + lane];
    float s = v;
    #pragma unroll
    for (int o = 1; o < 64; o <<= 1) s += __shfl_xor(s, o);
    float mu = s * (1.0f / 64.0f);
    float d = v - mu;
    float s2 = d * d;
    #pragma unroll
    for (int o = 1; o < 64; o <<= 1) s2 += __shfl_xor(s2, o);
    float var = s2 * (1.0f / 64.0f);
    out[token * CC + lane] = d * rsqrtf(var + 1e-5f) * g[lane] + b[lane];
}

// ---------------- GEMM: out[32-row tile, 64-col section] ----------------
// 256 thr: thread=(tc,tr) -> 2 rows x 4 cols. A transposed in LDS; W streamed
// (L1/L2 resident). OUTMODE: 0 plain (+GELU/+resid), 1 qkv split (q*0.25 /
// interleaved kv), 2 resid + fused LayerNorm (writes x2 and h2).
template<int K, int NC, bool GELU_ACT, bool RESID, int OUTMODE>
__global__ __launch_bounds__(256) void gemm_kernel(
    const float* __restrict__ A, const float* __restrict__ W,
    const float* __restrict__ bias, const float* __restrict__ resid,
    const float* __restrict__ lng, const float* __restrict__ lnb,
    float* __restrict__ out, float* __restrict__ out2)
{
    __shared__ float Ast[64][36];              // [k][row], transposed
    const int tid = threadIdx.x;
    const int t0 = blockIdx.x * 32;
    const int tc = tid & 15, tr = tid >> 4;
    const int c0 = tc * 4, r0 = tr * 2;
    const int c = blockIdx.y * 64 + c0;

    float acc[2][4];
    {
        const float4 b4 = *(const float4*)&bias[c];
        #pragma unroll
        for (int i = 0; i < 2; i++) { acc[i][0]=b4.x; acc[i][1]=b4.y; acc[i][2]=b4.z; acc[i][3]=b4.w; }
    }

    for (int k0 = 0; k0 < K; k0 += 64) {
        if (k0) __syncthreads();
        for (int i = tid; i < 32 * 64; i += 256) {
            int r = i >> 6, k = i & 63;
            Ast[k][r] = A[(t0 + r) * K + k0 + k];
        }
        __syncthreads();
        const float* wp = W + k0 * NC + c;
        #pragma unroll
        for (int k = 0; k < 64; k++) {
            float4 w = *(const float4*)&wp[k * NC];
            float2 a = *(const float2*)&Ast[k][r0];   // 16-lane broadcast, free
            acc[0][0] += a.x*w.x; acc[0][1] += a.x*w.y; acc[0][2] += a.x*w.z; acc[0][3] += a.x*w.w;
            acc[1][0] += a.y*w.x; acc[1][1] += a.y*w.y; acc[1][2] += a.y*w.z; acc[1][3] += a.y*w.w;
        }
    }

    if constexpr (OUTMODE == 1) {
        #pragma unroll
        for (int i = 0; i < 2; i++) {
            int row = t0 + r0 + i;
            if (blockIdx.y == 0) {       // q: scale by hd^-0.5
                float4 o = make_float4(acc[i][0]*0.25f, acc[i][1]*0.25f,
                                       acc[i][2]*0.25f, acc[i][3]*0.25f);
                *(float4*)&out[row * 64 + c0] = o;
            } else {                      // k->slot0, v->slot1 interleaved
                int off = (blockIdx.y == 1) ? 0 : 1;
                #pragma unroll
                for (int j = 0; j < 4; j++)
                    out2[row * 128 + (c0 + j) * 2 + off] = acc[i][j];
            }
        }
    } else if constexpr (OUTMODE == 2) {
        // o = acc + resid; out = o (x2); out2 = LayerNorm(o) (h2)
        float4 o[2];
        #pragma unroll
        for (int i = 0; i < 2; i++) {
            float4 rr = *(const float4*)&resid[(t0 + r0 + i) * 64 + c0];
            o[i] = make_float4(acc[i][0]+rr.x, acc[i][1]+rr.y, acc[i][2]+rr.z, acc[i][3]+rr.w);
        }
        float s0 = o[0].x+o[0].y+o[0].z+o[0].w;
        float s1 = o[1].x+o[1].y+o[1].z+o[1].w;
        float q0 = o[0].x*o[0].x+o[0].y*o[0].y+o[0].z*o[0].z+o[0].w*o[0].w;
        float q1 = o[1].x*o[1].x+o[1].y*o[1].y+o[1].z*o[1].z+o[1].w*o[1].w;
        #pragma unroll
        for (int m = 1; m < 16; m <<= 1) {   // 16 lanes (tc) hold the full row
            s0 += __shfl_xor(s0, m); q0 += __shfl_xor(q0, m);
            s1 += __shfl_xor(s1, m); q1 += __shfl_xor(q1, m);
        }
        float mu0 = s0*(1.f/64.f), mu1 = s1*(1.f/64.f);
        float rs0 = rsqrtf(q0*(1.f/64.f) - mu0*mu0 + 1e-5f);
        float rs1 = rsqrtf(q1*(1.f/64.f) - mu1*mu1 + 1e-5f);
        float4 g4 = *(const float4*)&lng[c0];
        float4 b4 = *(const float4*)&lnb[c0];
        float4 h0 = make_float4((o[0].x-mu0)*rs0*g4.x+b4.x, (o[0].y-mu0)*rs0*g4.y+b4.y,
                                (o[0].z-mu0)*rs0*g4.z+b4.z, (o[0].w-mu0)*rs0*g4.w+b4.w);
        float4 h1 = make_float4((o[1].x-mu1)*rs1*g4.x+b4.x, (o[1].y-mu1)*rs1*g4.y+b4.y,
                                (o[1].z-mu1)*rs1*g4.z+b4.z, (o[1].w-mu1)*rs1*g4.w+b4.w);
        *(float4*)&out[(t0+r0)*64 + c0] = o[0];
        *(float4*)&out[(t0+r0+1)*64 + c0] = o[1];
        *(float4*)&out2[(t0+r0)*64 + c0] = h0;
        *(float4*)&out2[(t0+r0+1)*64 + c0] = h1;
    } else {
        #pragma unroll
        for (int i = 0; i < 2; i++) {
            int row = t0 + r0 + i;
            float4 o = make_float4(acc[i][0], acc[i][1], acc[i][2], acc[i][3]);
            if constexpr (GELU_ACT) {
                o.x = 0.5f*o.x*(1.f+erff(o.x*0.70710678118f));
                o.y = 0.5f*o.y*(1.f+erff(o.y*0.70710678118f));
                o.z = 0.5f*o.z*(1.f+erff(o.z*0.70710678118f));
                o.w = 0.5f*o.w*(1.f+erff(o.w*0.70710678118f));
            }
            if constexpr (RESID) {
                float4 rr = *(const float4*)&resid[row * NC + c];
                o.x += rr.x; o.y += rr.y; o.z += rr.z; o.w += rr.w;
            }
            *(float4*)&out[row * NC + c] = o;
        }
    }
}

// ---------------- Neighborhood attention: wave = token, lane = (head, nbr) ----
// Each lane computes the FULL 16-dim q.k dot for one neighbor of its head:
// no per-neighbor shuffles, exp once per neighbor (not 16x). Final 4-round
// butterfly reduces (s, ov[16]) across the 16 lanes of each head group.
__global__ __launch_bounds__(256) void na_attn_kernel(
    const float* __restrict__ q, const float* __restrict__ kv,
    const float* __restrict__ rpb, float* __restrict__ out)
{
    int wave = threadIdx.x >> 6;
    int lane = threadIdx.x & 63;
    int token = blockIdx.x * 4 + wave;
    int head = lane >> 4, nb = lane & 15;

    int y = token / WW, x = token - y * WW;
    int gh = y % 3, ih = y / 3;
    int gw = x % 3, iw = x / 3;
    int sh = ih - 6; sh = sh < 0 ? 0 : (sh > 19 ? 19 : sh);
    int sw = iw - 6; sw = sw < 0 ? 0 : (sw > 19 ? 19 : sw);

    // q for this head: 16 floats (broadcast across the 16-lane group)
    float qv[16];
    {
        const float4* qp = (const float4*)(q + token * 64 + head * 16);
        #pragma unroll
        for (int j = 0; j < 4; j++) {
            float4 t = qp[j];
            qv[4*j] = t.x; qv[4*j+1] = t.y; qv[4*j+2] = t.z; qv[4*j+3] = t.w;
        }
    }
    const float* bias_h = rpb + head * 625;
    const int relw0 = sw - iw + 12, relh0 = sh - ih + 12;

    float ov[16];
    #pragma unroll
    for (int j = 0; j < 16; j++) ov[j] = 0.f;
    float s = 0.f;

    for (int it = 0; it < 11; it++) {
        int n = it * 16 + nb;
        if (n < 169) {
            int kh = (n * 79) >> 10;          // n/13 for n<169
            int kw = n - kh * 13;
            int ny = gh + 3 * (sh + kh);
            int nx = gw + 3 * (sw + kw);
            // per-channel interleaved (k,v): head chunk = 32 contiguous floats
            const float4* kp = (const float4*)(kv + (ny * WW + nx) * 128 + head * 32);
            float b = bias_h[(relh0 + kh) * 25 + (relw0 + kw)];
            float p = 0.f;
            float4 f[8];
            #pragma unroll
            for (int j = 0; j < 8; j++) f[j] = kp[j];
            #pragma unroll
            for (int j = 0; j < 8; j++) { p += qv[2*j]*f[j].x + qv[2*j+1]*f[j].z; }
            float e = __expf(p + b);
            s += e;
            #pragma unroll
            for (int j = 0; j < 8; j++) { ov[2*j] += e*f[j].y; ov[2*j+1] += e*f[j].w; }
        }
    }

    // reduce s and ov[16] across the 16 lanes of this head group
    #pragma unroll
    for (int m = 1; m < 16; m <<= 1) {
        s += __shfl_xor(s, m);
        #pragma unroll
        for (int j = 0; j < 16; j++) ov[j] += __shfl_xor(ov[j], m);
    }
    // lane nb outputs channel nb of its head
    float r = ov[0];
    #pragma unroll
    for (int j = 1; j < 16; j++) r = (nb == j) ? ov[j] : r;
    out[token * 64 + head * 16 + nb] = r / s;
}

extern "C" void kernel_launch(void* const* d_in, const int* in_sizes, int n_in,
                              void* d_out, int out_size, void* d_ws, size_t ws_size,
                              hipStream_t stream) {
    const float* x       = (const float*)d_in[0];
    const float* norm1_g = (const float*)d_in[1];
    const float* norm1_b = (const float*)d_in[2];
    const float* qkv_w   = (const float*)d_in[3];
    const float* qkv_b   = (const float*)d_in[4];
    const float* rpb     = (const float*)d_in[5];
    const float* proj_w  = (const float*)d_in[6];
    const float* proj_b  = (const float*)d_in[7];
    const float* norm2_g = (const float*)d_in[8];
    const float* norm2_b = (const float*)d_in[9];
    const float* fc1_w   = (const float*)d_in[10];
    const float* fc1_b   = (const float*)d_in[11];
    const float* fc2_w   = (const float*)d_in[12];
    const float* fc2_b   = (const float*)d_in[13];
    float* out = (float*)d_out;

    float* ws = (float*)d_ws;
    float* h1       = ws;                      // 9216*64
    float* qbuf     = h1 + NTOK * 64;          // 9216*64
    float* kvbuf    = qbuf + NTOK * 64;        // 9216*128 (k,v interleaved)
    float* attn_out = kvbuf + NTOK * 128;      // 9216*64
    float* x2       = attn_out + NTOK * 64;    // 9216*64
    float* h2       = x2 + NTOK * 64;          // 9216*64
    float* hidden   = h2 + NTOK * 64;          // 9216*256

    dim3 blk(256);
    // 1. LN1
    ln_kernel<<<NTOK / 4, blk, 0, stream>>>(x, norm1_g, norm1_b, h1);
    // 2. q/k/v = h1 @ qkv_w + qkv_b  (q scaled; kv interleaved)
    gemm_kernel<64, 192, false, false, 1>
        <<<dim3(NTOK/32, 3), blk, 0, stream>>>(h1, qkv_w, qkv_b, nullptr,
                                               nullptr, nullptr, qbuf, kvbuf);
    // 3. neighborhood attention
    na_attn_kernel<<<NTOK/4, blk, 0, stream>>>(qbuf, kvbuf, rpb, attn_out);
    // 4. x2 = x + attn_out @ proj_w + proj_b ; h2 = LN2(x2)   (fused)
    gemm_kernel<64, 64, false, true, 2>
        <<<dim3(NTOK/32, 1), blk, 0, stream>>>(attn_out, proj_w, proj_b, x,
                                               norm2_g, norm2_b, x2, h2);
    // 5. hidden = gelu(h2 @ fc1_w + fc1_b)
    gemm_kernel<64, 256, true, false, 0>
        <<<dim3(NTOK/32, 4), blk, 0, stream>>>(h2, fc1_w, fc1_b, nullptr,
                                               nullptr, nullptr, hidden, nullptr);
    // 6. out = x2 + hidden @ fc2_w + fc2_b
    gemm_kernel<256, 64, false, true, 0>
        <<<dim3(NTOK/32, 1), blk, 0, stream>>>(hidden, fc2_w, fc2_b, x2,
                                               nullptr, nullptr, out, nullptr);
}

// Round 6
// 235.979 us; speedup vs baseline: 1.1755x; 1.1755x over previous
//
#include <hip/hip_runtime.h>
#include <math.h>

#define HH 96
#define WW 96
#define CC 64
#define NH 4
#define HD 16
#define KS 13
#define NTOK (HH*WW)
#define NBR (KS*KS)       // 169
#define PAD 171           // NBR + 2: conflict-free transposed LDS

// ---------------- LayerNorm: one wave (64 lanes) per token ----------------
__global__ __launch_bounds__(256) void ln_kernel(const float* __restrict__ x,
                                                 const float* __restrict__ g,
                                                 const float* __restrict__ b,
                                                 float* __restrict__ out) {
    int wave = threadIdx.x >> 6;
    int lane = threadIdx.x & 63;
    int token = blockIdx.x * 4 + wave;
    float v = x[token * CC + lane];
    float s = v;
    #pragma unroll
    for (int o = 1; o < 64; o <<= 1) s += __shfl_xor(s, o);
    float mu = s * (1.0f / 64.0f);
    float d = v - mu;
    float s2 = d * d;
    #pragma unroll
    for (int o = 1; o < 64; o <<= 1) s2 += __shfl_xor(s2, o);
    float var = s2 * (1.0f / 64.0f);
    out[token * CC + lane] = d * rsqrtf(var + 1e-5f) * g[lane] + b[lane];
}

// ---------------- GEMM (R2-proven config): out = A[M,K] @ W[K,NC] + bias -----
// 32x64 tile/block, 2 rows x 4 cols per thread, A transposed in LDS (+2 pad),
// W streamed from global (L1/L2 resident).
template<int K, int NC, bool GELU_ACT, bool RESID, bool QSCALE>
__global__ __launch_bounds__(256) void gemm_kernel(const float* __restrict__ A,
                                                   const float* __restrict__ W,
                                                   const float* __restrict__ bias,
                                                   const float* __restrict__ resid,
                                                   float* __restrict__ out) {
    __shared__ float Ast[K][34];
    const int t0 = blockIdx.x * 32;
    const int tc = threadIdx.x & 15;
    const int tr = threadIdx.x >> 4;
    const int r0 = tr * 2;
    const int c  = blockIdx.y * 64 + tc * 4;

    for (int i = threadIdx.x; i < 32 * K; i += 256) {
        int r = i / K, cc = i % K;
        Ast[cc][r] = A[t0 * K + i];
    }
    __syncthreads();

    float4 b4 = *(const float4*)&bias[c];
    float4 acc0 = b4, acc1 = b4;
    #pragma unroll 8
    for (int k = 0; k < K; k++) {
        float2 a = *(const float2*)&Ast[k][r0];
        float4 w = *(const float4*)&W[k * NC + c];
        acc0.x += a.x * w.x; acc0.y += a.x * w.y; acc0.z += a.x * w.z; acc0.w += a.x * w.w;
        acc1.x += a.y * w.x; acc1.y += a.y * w.y; acc1.z += a.y * w.z; acc1.w += a.y * w.w;
    }

    if (QSCALE && blockIdx.y == 0) {  // q section scaled by hd^-0.5
        acc0.x *= 0.25f; acc0.y *= 0.25f; acc0.z *= 0.25f; acc0.w *= 0.25f;
        acc1.x *= 0.25f; acc1.y *= 0.25f; acc1.z *= 0.25f; acc1.w *= 0.25f;
    }
    if (GELU_ACT) {
        #define GELU1(v) v = 0.5f * v * (1.0f + erff(v * 0.70710678118f))
        GELU1(acc0.x); GELU1(acc0.y); GELU1(acc0.z); GELU1(acc0.w);
        GELU1(acc1.x); GELU1(acc1.y); GELU1(acc1.z); GELU1(acc1.w);
        #undef GELU1
    }
    if (RESID) {
        float4 r0v = *(const float4*)&resid[(t0 + r0) * NC + c];
        float4 r1v = *(const float4*)&resid[(t0 + r0 + 1) * NC + c];
        acc0.x += r0v.x; acc0.y += r0v.y; acc0.z += r0v.z; acc0.w += r0v.w;
        acc1.x += r1v.x; acc1.y += r1v.y; acc1.z += r1v.z; acc1.w += r1v.w;
    }
    *(float4*)&out[(t0 + r0) * NC + c] = acc0;
    *(float4*)&out[(t0 + r0 + 1) * NC + c] = acc1;
}

// ---------------- Neighborhood attention: block = token, wave = head ---------
// Window k/v staged in LDS transposed [channel][neighbor] (pad 171 ->
// conflict-free b32 in QK and PV). Lane = neighbor for QK (full 16-dim dot
// in-register, ONE exp per neighbor); lane = (channel, quarter) for PV.
// qkv: [token][192] = q|k|v sections (q pre-scaled by 0.25).
__global__ __launch_bounds__(256) void na_attn_kernel(
    const float* __restrict__ qkv, const float* __restrict__ rpb,
    float* __restrict__ out)
{
    __shared__ float kst[64][PAD];   // k window, then v window (reused)
    __shared__ float est[NH][PAD];   // exp(logit) per head
    const int tid = threadIdx.x;
    const int token = blockIdx.x;
    const int h = tid >> 6;          // wave = head
    const int lane = tid & 63;

    int y = token / WW, x = token - y * WW;
    int gh = y % 3, ih = y / 3;
    int gw = x % 3, iw = x / 3;
    int sh = ih - 6; sh = sh < 0 ? 0 : (sh > 19 ? 19 : sh);
    int sw = iw - 6; sw = sw < 0 ? 0 : (sw > 19 ? 19 : sw);
    const int relh0 = sh - ih + 12, relw0 = sw - iw + 12;
    const int base = (gh + 3 * sh) * WW + gw + 3 * sw;   // neighbor(kh,kw) = base + 3*(kh*WW + kw)

    // q for this head (wave-uniform load)
    float q[16];
    {
        const float4* qp = (const float4*)(qkv + token * 192 + h * 16);
        #pragma unroll
        for (int j = 0; j < 4; j++) {
            float4 t = qp[j];
            q[4*j] = t.x; q[4*j+1] = t.y; q[4*j+2] = t.z; q[4*j+3] = t.w;
        }
    }

    // ---- stage K (coalesced float4 read, transposed b32 writes) ----
    for (int i = tid; i < NBR * 16; i += 256) {
        int n = i >> 4, c4 = (i & 15) * 4;
        int kh = (n * 79) >> 10, kw = n - kh * 13;      // n/13, n%13
        int nt = base + 3 * (kh * WW + kw);
        float4 t = *(const float4*)&qkv[nt * 192 + 64 + c4];
        kst[c4 + 0][n] = t.x; kst[c4 + 1][n] = t.y;
        kst[c4 + 2][n] = t.z; kst[c4 + 3][n] = t.w;
    }
    __syncthreads();

    // ---- QK + bias + exp (lane = neighbor; one exp per neighbor) ----
    float s = 0.f;
    #pragma unroll
    for (int it = 0; it < 3; it++) {
        int n = lane + it * 64;
        if (it < 2 || n < NBR) {
            float p = 0.f;
            #pragma unroll
            for (int j = 0; j < 16; j++) p += q[j] * kst[h * 16 + j][n];
            int kh = (n * 79) >> 10, kw = n - kh * 13;
            float b = rpb[h * 625 + (relh0 + kh) * 25 + relw0 + kw];
            float e = __expf(p + b);
            est[h][n] = e;
            s += e;
        }
    }
    #pragma unroll
    for (int m = 1; m < 64; m <<= 1) s += __shfl_xor(s, m);
    __syncthreads();   // all QK reads done -> safe to overwrite with V

    // ---- stage V (same layout, reuse kst) ----
    for (int i = tid; i < NBR * 16; i += 256) {
        int n = i >> 4, c4 = (i & 15) * 4;
        int kh = (n * 79) >> 10, kw = n - kh * 13;
        int nt = base + 3 * (kh * WW + kw);
        float4 t = *(const float4*)&qkv[nt * 192 + 128 + c4];
        kst[c4 + 0][n] = t.x; kst[c4 + 1][n] = t.y;
        kst[c4 + 2][n] = t.z; kst[c4 + 3][n] = t.w;
    }
    __syncthreads();

    // ---- PV: lane = (channel 0..15, quarter 0..3) ----
    int cc = lane & 15, nsub = lane >> 4;
    float acc = 0.f;
    for (int n = nsub; n < NBR; n += 4)
        acc += est[h][n] * kst[cc][n];       // est: broadcast; kst: conflict-free
    acc += __shfl_xor(acc, 16);
    acc += __shfl_xor(acc, 32);
    if (nsub == 0) out[token * 64 + h * 16 + cc] = acc / s;
}

extern "C" void kernel_launch(void* const* d_in, const int* in_sizes, int n_in,
                              void* d_out, int out_size, void* d_ws, size_t ws_size,
                              hipStream_t stream) {
    const float* x       = (const float*)d_in[0];
    const float* norm1_g = (const float*)d_in[1];
    const float* norm1_b = (const float*)d_in[2];
    const float* qkv_w   = (const float*)d_in[3];
    const float* qkv_b   = (const float*)d_in[4];
    const float* rpb     = (const float*)d_in[5];
    const float* proj_w  = (const float*)d_in[6];
    const float* proj_b  = (const float*)d_in[7];
    const float* norm2_g = (const float*)d_in[8];
    const float* norm2_b = (const float*)d_in[9];
    const float* fc1_w   = (const float*)d_in[10];
    const float* fc1_b   = (const float*)d_in[11];
    const float* fc2_w   = (const float*)d_in[12];
    const float* fc2_b   = (const float*)d_in[13];
    float* out = (float*)d_out;

    float* ws = (float*)d_ws;
    float* h1       = ws;                      // 9216*64
    float* qkvbuf   = h1 + NTOK * 64;          // 9216*192 (q|k|v)
    float* attn_out = qkvbuf + NTOK * 192;     // 9216*64
    float* x2       = attn_out + NTOK * 64;    // 9216*64
    float* h2       = x2 + NTOK * 64;          // 9216*64
    float* hidden   = h2 + NTOK * 64;          // 9216*256

    dim3 blk(256);
    // 1. LN1
    ln_kernel<<<NTOK / 4, blk, 0, stream>>>(x, norm1_g, norm1_b, h1);
    // 2. qkv = h1 @ qkv_w + qkv_b  (q scaled)
    gemm_kernel<64, 192, false, false, true>
        <<<dim3(NTOK/32, 3), blk, 0, stream>>>(h1, qkv_w, qkv_b, nullptr, qkvbuf);
    // 3. neighborhood attention (LDS-staged window)
    na_attn_kernel<<<NTOK, blk, 0, stream>>>(qkvbuf, rpb, attn_out);
    // 4. x2 = x + attn_out @ proj_w + proj_b
    gemm_kernel<64, 64, false, true, false>
        <<<dim3(NTOK/32, 1), blk, 0, stream>>>(attn_out, proj_w, proj_b, x, x2);
    // 5. LN2
    ln_kernel<<<NTOK / 4, blk, 0, stream>>>(x2, norm2_g, norm2_b, h2);
    // 6. hidden = gelu(h2 @ fc1_w + fc1_b)
    gemm_kernel<64, 256, true, false, false>
        <<<dim3(NTOK/32, 4), blk, 0, stream>>>(h2, fc1_w, fc1_b, nullptr, hidden);
    // 7. out = x2 + hidden @ fc2_w + fc2_b
    gemm_kernel<256, 64, false, true, false>
        <<<dim3(NTOK/32, 1), blk, 0, stream>>>(hidden, fc2_w, fc2_b, x2, out);
}